// Round 1
// baseline (535.451 us; speedup 1.0000x reference)
//
#include <hip/hip_runtime.h>

#define CH   224   // channels (C == T == 224)
#define TT    32   // t-tile per block
#define KCH   32   // c-chunk staged per iteration
#define CPAD 228   // a_lds row stride in floats (mult of 4 -> b128 aligned)

// ---------------------------------------------------------------------------
// Kernel 0: wsqh[k] = 0.5 * sum_c w[k][c]^2   (224 blocks x 1 wave)
// ---------------------------------------------------------------------------
__global__ void wsq_kernel(const float* __restrict__ w, float* __restrict__ wsqh) {
    const int k    = blockIdx.x;
    const int lane = threadIdx.x;          // 0..63
    float s = 0.f;
    for (int c = lane; c < CH; c += 64) {
        float v = w[k * CH + c];
        s = fmaf(v, v, s);
    }
    for (int off = 32; off > 0; off >>= 1)
        s += __shfl_down(s, off);
    if (lane == 0) wsqh[k] = 0.5f * s;
}

// ---------------------------------------------------------------------------
// Kernel 1: per block: b fixed, 32 t's, all 224 k's.
//   score[t][k] = dot(x[b,t], w[k]) - 0.5*||w[k]||^2 ; bmu = argmax (tie->min k)
//   out[b, k, t] = (bmu[t] == k)
// Thread layout: kg = tid&31 owns k = kg*7 .. kg*7+6 ; tg = tid>>5 owns
// t = tg*4 .. tg*4+3  -> 4x7 fp32 accumulators.
// ---------------------------------------------------------------------------
__global__ __launch_bounds__(256, 2) void som_kernel(
    const float* __restrict__ inp, const float* __restrict__ w,
    const float* __restrict__ wsqh, float* __restrict__ out)
{
    __shared__ float a_lds[TT * CPAD];        // 32*228*4 = 29184 B, [t][c]
    __shared__ float w_lds[CH * KCH];         // 224*32*4 = 28672 B, xor-swizzled
    __shared__ int   bmu_lds[TT];

    const int tid = threadIdx.x;
    const int b   = blockIdx.x / (CH / TT);   // 0..511
    const int t0  = (blockIdx.x % (CH / TT)) * TT;

    // ---- stage A: inp[b, :, t0:t0+32] -> a_lds[t][c] (transpose) ----
    {
        const int tl = (tid & 7) * 4;         // 0,4,..,28
        const int c0 = tid >> 3;              // 0..31
        const float* src = inp + (size_t)b * CH * CH + t0 + tl;
        #pragma unroll
        for (int j = 0; j < 7; ++j) {
            const int c = c0 + j * 32;
            const float4 v = *(const float4*)(src + (size_t)c * CH);
            a_lds[(tl + 0) * CPAD + c] = v.x;
            a_lds[(tl + 1) * CPAD + c] = v.y;
            a_lds[(tl + 2) * CPAD + c] = v.z;
            a_lds[(tl + 3) * CPAD + c] = v.w;
        }
    }

    const int kg = tid & 31;                  // k-group
    const int tg = tid >> 5;                  // t-group
    float acc[4][7];
    #pragma unroll
    for (int i = 0; i < 4; ++i)
        #pragma unroll
        for (int j = 0; j < 7; ++j) acc[i][j] = 0.f;

    for (int ch = 0; ch < 7; ++ch) {
        const int cbase = ch * KCH;
        // load next w chunk to regs (in flight across the barrier)
        float4 wreg[7];
        int    wk[7], wc4[7];
        #pragma unroll
        for (int j = 0; j < 7; ++j) {
            const int f = tid + 256 * j;      // 0..1791
            wk[j]  = f >> 3;                  // k row 0..223
            wc4[j] = f & 7;                   // float4 col 0..7
            wreg[j] = *(const float4*)(w + (size_t)wk[j] * CH + cbase + wc4[j] * 4);
        }
        __syncthreads();                      // previous chunk fully consumed
        #pragma unroll
        for (int j = 0; j < 7; ++j) {
            const int swz = wc4[j] ^ (wk[j] & 7);           // xor swizzle
            *(float4*)(w_lds + wk[j] * KCH + swz * 4) = wreg[j];
        }
        __syncthreads();

        // compute: 8 steps of 4 c's
        #pragma unroll
        for (int s4 = 0; s4 < 8; ++s4) {
            float4 av[4];
            #pragma unroll
            for (int i = 0; i < 4; ++i)
                av[i] = *(const float4*)(a_lds + (tg * 4 + i) * CPAD + cbase + s4 * 4);
            #pragma unroll
            for (int j = 0; j < 7; ++j) {
                const int k   = kg * 7 + j;
                const int swz = s4 ^ (k & 7);
                const float4 wv = *(const float4*)(w_lds + k * KCH + swz * 4);
                #pragma unroll
                for (int i = 0; i < 4; ++i) {
                    acc[i][j] = fmaf(av[i].x, wv.x, acc[i][j]);
                    acc[i][j] = fmaf(av[i].y, wv.y, acc[i][j]);
                    acc[i][j] = fmaf(av[i].z, wv.z, acc[i][j]);
                    acc[i][j] = fmaf(av[i].w, wv.w, acc[i][j]);
                }
            }
        }
    }

    // ---- argmax(score), tie -> smallest k ----
    float wq[7];
    #pragma unroll
    for (int j = 0; j < 7; ++j) wq[j] = wsqh[kg * 7 + j];

    #pragma unroll
    for (int i = 0; i < 4; ++i) {
        float bs = acc[i][0] - wq[0];
        int   bk = kg * 7;
        #pragma unroll
        for (int j = 1; j < 7; ++j) {
            const float s = acc[i][j] - wq[j];
            if (s > bs) { bs = s; bk = kg * 7 + j; }   // strict: keep smaller k
        }
        #pragma unroll
        for (int m = 1; m < 32; m <<= 1) {
            const float so = __shfl_xor(bs, m);
            const int   ko = __shfl_xor(bk, m);
            if (so > bs || (so == bs && ko < bk)) { bs = so; bk = ko; }
        }
        if (kg == 0) bmu_lds[tg * 4 + i] = bk;
    }
    __syncthreads();

    // ---- one-hot write: out[b, k, t0 + t] ----
    {
        float* dst = out + (size_t)b * CH * CH + t0;
        #pragma unroll
        for (int j = 0; j < 7; ++j) {
            const int f  = tid + 256 * j;
            const int k  = f >> 3;
            const int t4 = (f & 7) * 4;
            float4 v;
            v.x = (bmu_lds[t4 + 0] == k) ? 1.f : 0.f;
            v.y = (bmu_lds[t4 + 1] == k) ? 1.f : 0.f;
            v.z = (bmu_lds[t4 + 2] == k) ? 1.f : 0.f;
            v.w = (bmu_lds[t4 + 3] == k) ? 1.f : 0.f;
            *(float4*)(dst + (size_t)k * CH + t4) = v;
        }
    }
}

extern "C" void kernel_launch(void* const* d_in, const int* in_sizes, int n_in,
                              void* d_out, int out_size, void* d_ws, size_t ws_size,
                              hipStream_t stream) {
    const float* inp = (const float*)d_in[0];     // (512, 224, 224) fp32
    const float* w   = (const float*)d_in[1];     // (224, 224) fp32
    float* wsqh = (float*)d_ws;                   // 224 floats scratch
    float* out  = (float*)d_out;                  // (512, 1, 224, 224) fp32

    const int batch = in_sizes[0] / (CH * CH);    // 512

    wsq_kernel<<<CH, 64, 0, stream>>>(w, wsqh);
    som_kernel<<<batch * (CH / TT), 256, 0, stream>>>(inp, w, wsqh, out);
}

// Round 4
// 263.976 us; speedup vs baseline: 2.0284x; 2.0284x over previous
//
#include <hip/hip_runtime.h>

#define CH 224
#define BK 32           // K-chunk (one 16x16x32 MFMA step)
#define MB 128          // rows (points) per block
#define MW 32           // rows per wave
#define NF 14           // n-fragments = 224/16
#define EPS 5e-4f       // approx-score gap below which we re-resolve exactly

typedef __attribute__((ext_vector_type(8))) short bf16x8;
typedef __attribute__((ext_vector_type(4))) float f32x4;

__device__ inline unsigned short f2bf(float x) {
    unsigned int u = __builtin_bit_cast(unsigned int, x);
    return (unsigned short)((u + 0x7FFFu + ((u >> 16) & 1u)) >> 16);   // RNE
}
__device__ inline float bf2f(unsigned short h) {
    unsigned int u = ((unsigned int)h) << 16;
    return __builtin_bit_cast(float, u);
}

// ---------------------------------------------------------------------------
// Prep: w (fp32) -> whi/wlo (bf16 split) + wsqh[k] = 0.5*||w_k||^2
// (wsqh reduction order identical to round-1's proven-matching kernel)
// ---------------------------------------------------------------------------
__global__ void wprep_kernel(const float* __restrict__ w,
                             unsigned short* __restrict__ whi,
                             unsigned short* __restrict__ wlo,
                             float* __restrict__ wsqh) {
    const int k = blockIdx.x, lane = threadIdx.x;    // 224 blocks x 64
    float s = 0.f;
    for (int c = lane; c < CH; c += 64) {
        const float v = w[k * CH + c];
        const unsigned short h = f2bf(v);
        whi[k * CH + c] = h;
        wlo[k * CH + c] = f2bf(v - bf2f(h));
        s = fmaf(v, v, s);
    }
    for (int off = 32; off > 0; off >>= 1) s += __shfl_down(s, off);
    if (lane == 0) wsqh[k] = 0.5f * s;
}

// ---------------------------------------------------------------------------
// Main: rows m = b*224 + t. Block: 128 rows x 224 codes. score = x.w - wsq/2,
// via 3x bf16 MFMA (hi*hi + hi*lo + lo*hi), fused argmax + one-hot.
// ---------------------------------------------------------------------------
__global__ __launch_bounds__(256, 2) void som_mfma(
    const float* __restrict__ inp, const float* __restrict__ w,
    const unsigned short* __restrict__ whi, const unsigned short* __restrict__ wlo,
    const float* __restrict__ wsqh, float* __restrict__ out)
{
    __shared__ __align__(16) unsigned short Wl[2 * CH * BK];   // 28672 B, [hl][k][c] swizzled
    __shared__ __align__(16) unsigned short Xl[4 * 2 * MW * BK]; // 16384 B, per-wave [hl][t][c] swizzled
    __shared__ int bmu_sh[MB];
    __shared__ unsigned char flg_sh[MB];

    const int tid  = threadIdx.x;
    const int lane = tid & 63;
    const int wv   = tid >> 6;
    const int m0   = blockIdx.x * MB;
    const int mw   = m0 + wv * MW;          // wave rows are 32-aligned -> single b
    const int bb   = mw / CH;
    const int t0   = mw % CH;

    const int col = lane & 15;
    const int g   = lane >> 4;

    // X staging map: instr j: c_loc = j*8 + (lane>>3), t = (lane&7)*4 .. +3
    const int xs_c = lane >> 3;
    const int xs_t = (lane & 7) * 4;

    unsigned short* Xw = Xl + wv * 2048;

    f32x4 acc[2][NF];
    #pragma unroll
    for (int mf = 0; mf < 2; ++mf)
        #pragma unroll
        for (int nf = 0; nf < NF; ++nf)
            acc[mf][nf] = (f32x4){0.f, 0.f, 0.f, 0.f};

    for (int ch = 0; ch < 7; ++ch) {
        const int cb = ch * BK;

        // ---- prefetch X chunk (own 32 rows x 32 c, fp32, transpose-read) ----
        float4 xv[4];
        #pragma unroll
        for (int j = 0; j < 4; ++j) {
            const int c = cb + j * 8 + xs_c;
            xv[j] = *(const float4*)(inp + (size_t)bb * CH * CH + (size_t)c * CH + t0 + xs_t);
        }

        __syncthreads();   // everyone done READING Wl of previous chunk

        // ---- stage W chunk: [2][224][32] bf16, group-swizzled (28 x 16B/wave-set) ----
        #pragma unroll
        for (int j2 = wv; j2 < 28; j2 += 4) {
            const int hl  = j2 / 14;
            const int r0  = (j2 % 14) * 16;
            const int row = r0 + (lane >> 2);
            const int gg  = (lane & 3) ^ (row & 3);      // source group for slot (lane&3)
            const bf16x8 v = *(const bf16x8*)((hl ? wlo : whi) + (size_t)row * CH + cb + gg * 8);
            *(bf16x8*)(Wl + hl * (CH * BK) + row * BK + (lane & 3) * 8) = v;
        }

        // ---- convert + write X (wave-local region, swizzled [t][c]) ----
        #pragma unroll
        for (int j = 0; j < 4; ++j) {
            const float xe[4] = {xv[j].x, xv[j].y, xv[j].z, xv[j].w};
            #pragma unroll
            for (int i = 0; i < 4; ++i) {
                const int t_loc = xs_t + i;              // t_loc&3 == i
                const int base  = t_loc * BK + ((j ^ i) << 3) + (xs_c & 7);
                const unsigned short h = f2bf(xe[i]);
                Xw[base]        = h;
                Xw[1024 + base] = f2bf(xe[i] - bf2f(h));
            }
        }

        __syncthreads();   // Wl + own X visible

        // ---- fragments + MFMA ----
        bf16x8 af[2][2];   // [hl][mf]
        #pragma unroll
        for (int hl = 0; hl < 2; ++hl)
            #pragma unroll
            for (int mf = 0; mf < 2; ++mf) {
                const int t_loc = mf * 16 + col;
                af[hl][mf] = *(const bf16x8*)(Xw + hl * 1024 + t_loc * BK + ((g ^ (col & 3)) << 3));
            }
        #pragma unroll
        for (int nf = 0; nf < NF; ++nf) {
            const int kc = nf * 16 + col;
            const int so = (g ^ (kc & 3)) << 3;
            const bf16x8 bh = *(const bf16x8*)(Wl + kc * BK + so);
            const bf16x8 bl = *(const bf16x8*)(Wl + CH * BK + kc * BK + so);
            #pragma unroll
            for (int mf = 0; mf < 2; ++mf) {
                acc[mf][nf] = __builtin_amdgcn_mfma_f32_16x16x32_bf16(af[0][mf], bh, acc[mf][nf], 0, 0, 0);
                acc[mf][nf] = __builtin_amdgcn_mfma_f32_16x16x32_bf16(af[0][mf], bl, acc[mf][nf], 0, 0, 0);
                acc[mf][nf] = __builtin_amdgcn_mfma_f32_16x16x32_bf16(af[1][mf], bh, acc[mf][nf], 0, 0, 0);
            }
        }
    }

    // ---- fused argmax with top-2 gap flag (C layout: col=lane&15, row=g*4+reg) ----
    float wq[NF];
    #pragma unroll
    for (int nf = 0; nf < NF; ++nf) wq[nf] = wsqh[nf * 16 + col];

    #pragma unroll
    for (int mf = 0; mf < 2; ++mf) {
        #pragma unroll
        for (int r = 0; r < 4; ++r) {
            float v1 = -1e30f, v2 = -1e30f; int k1 = 0;
            #pragma unroll
            for (int nf = 0; nf < NF; ++nf) {
                const float s = acc[mf][nf][r] - wq[nf];
                const int k = nf * 16 + col;
                if (s > v1 || (s == v1 && k < k1)) { v2 = v1; v1 = s; k1 = k; }
                else if (s > v2) v2 = s;
            }
            #pragma unroll
            for (int mm = 1; mm < 16; mm <<= 1) {
                const float ov1 = __shfl_xor(v1, mm);
                const int   ok1 = __shfl_xor(k1, mm);
                const float ov2 = __shfl_xor(v2, mm);
                if (ov1 > v1 || (ov1 == v1 && ok1 < k1)) { v2 = fmaxf(v1, ov2); v1 = ov1; k1 = ok1; }
                else                                     { v2 = fmaxf(v2, ov1); }
            }
            if (col == 0) {
                const int trow = mf * 16 + g * 4 + r;
                bmu_sh[wv * MW + trow] = k1;
                flg_sh[wv * MW + trow] = (v1 - v2 < EPS) ? 1 : 0;
            }
        }
    }

    // ---- exact re-resolve of flagged rows (rare; replicates round-1 math) ----
    for (int tl = 0; tl < MW; ++tl) {
        if (!flg_sh[wv * MW + tl]) continue;
        const int tg = t0 + tl;
        const float* xp = inp + (size_t)bb * CH * CH + tg;
        float s0 = 0.f, s1 = 0.f, s2 = 0.f, s3 = 0.f;
        const int k0 = lane, k1a = lane + 64, k2 = lane + 128, k3 = lane + 192;
        for (int c = 0; c < CH; c += 4) {
            float xc[4];
            #pragma unroll
            for (int i = 0; i < 4; ++i) xc[i] = xp[(size_t)(c + i) * CH];
            const float4 w0 = *(const float4*)(w + (size_t)k0  * CH + c);
            const float4 w1 = *(const float4*)(w + (size_t)k1a * CH + c);
            const float4 w2 = *(const float4*)(w + (size_t)k2  * CH + c);
            s0 = fmaf(xc[0], w0.x, s0); s0 = fmaf(xc[1], w0.y, s0); s0 = fmaf(xc[2], w0.z, s0); s0 = fmaf(xc[3], w0.w, s0);
            s1 = fmaf(xc[0], w1.x, s1); s1 = fmaf(xc[1], w1.y, s1); s1 = fmaf(xc[2], w1.z, s1); s1 = fmaf(xc[3], w1.w, s1);
            s2 = fmaf(xc[0], w2.x, s2); s2 = fmaf(xc[1], w2.y, s2); s2 = fmaf(xc[2], w2.z, s2); s2 = fmaf(xc[3], w2.w, s2);
            if (k3 < CH) {
                const float4 w3 = *(const float4*)(w + (size_t)k3 * CH + c);
                s3 = fmaf(xc[0], w3.x, s3); s3 = fmaf(xc[1], w3.y, s3); s3 = fmaf(xc[2], w3.z, s3); s3 = fmaf(xc[3], w3.w, s3);
            }
        }
        float bs = -1e30f; int bk = 1 << 30;
        {
            const float c0v = s0 - wsqh[k0];
            if (c0v > bs || (c0v == bs && k0 < bk)) { bs = c0v; bk = k0; }
            const float c1v = s1 - wsqh[k1a];
            if (c1v > bs || (c1v == bs && k1a < bk)) { bs = c1v; bk = k1a; }
            const float c2v = s2 - wsqh[k2];
            if (c2v > bs || (c2v == bs && k2 < bk)) { bs = c2v; bk = k2; }
            if (k3 < CH) {
                const float c3v = s3 - wsqh[k3];
                if (c3v > bs || (c3v == bs && k3 < bk)) { bs = c3v; bk = k3; }
            }
        }
        for (int mm = 1; mm < 64; mm <<= 1) {
            const float ob = __shfl_xor(bs, mm);
            const int   ok = __shfl_xor(bk, mm);
            if (ob > bs || (ob == bs && ok < bk)) { bs = ob; bk = ok; }
        }
        if (lane == 0) bmu_sh[wv * MW + tl] = bk;
    }

    __syncthreads();

    // ---- one-hot write: out[b, k, t] ----
    #pragma unroll
    for (int j = 0; j < 28; ++j) {
        const int f  = tid + 256 * j;       // 0..7167
        const int k  = f >> 5;              // 0..223
        const int rg = f & 31;              // 4-row group (never crosses b)
        const int m  = m0 + rg * 4;
        const int b2 = m / CH, t = m % CH;
        float4 v;
        v.x = (bmu_sh[rg * 4 + 0] == k) ? 1.f : 0.f;
        v.y = (bmu_sh[rg * 4 + 1] == k) ? 1.f : 0.f;
        v.z = (bmu_sh[rg * 4 + 2] == k) ? 1.f : 0.f;
        v.w = (bmu_sh[rg * 4 + 3] == k) ? 1.f : 0.f;
        *(float4*)(out + (size_t)b2 * CH * CH + (size_t)k * CH + t) = v;
    }
}

extern "C" void kernel_launch(void* const* d_in, const int* in_sizes, int n_in,
                              void* d_out, int out_size, void* d_ws, size_t ws_size,
                              hipStream_t stream) {
    const float* inp = (const float*)d_in[0];   // (512, 224, 224) fp32
    const float* w   = (const float*)d_in[1];   // (224, 224) fp32
    float* out = (float*)d_out;

    unsigned short* whi = (unsigned short*)d_ws;            // 224*224 bf16
    unsigned short* wlo = whi + CH * CH;                    // 224*224 bf16
    float* wsqh = (float*)(wlo + CH * CH);                  // 224 fp32

    const int batch = in_sizes[0] / (CH * CH);              // 512
    const int mtot  = batch * CH;                           // 114688

    wprep_kernel<<<CH, 64, 0, stream>>>(w, whi, wlo, wsqh);
    som_mfma<<<mtot / MB, 256, 0, stream>>>(inp, w, whi, wlo, wsqh, out);
}

// Round 6
// 235.271 us; speedup vs baseline: 2.2759x; 1.1220x over previous
//
#include <hip/hip_runtime.h>

#define CH 224
#define MB 128          // rows (points) per block
#define NF 14           // n-fragments = 224/16
#define EPS 5e-4f       // approx-score gap below which we re-resolve exactly

typedef __attribute__((ext_vector_type(8))) short bf16x8;
typedef __attribute__((ext_vector_type(4))) float f32x4;

__device__ inline unsigned short f2bf(float x) {
    unsigned int u = __builtin_bit_cast(unsigned int, x);
    return (unsigned short)((u + 0x7FFFu + ((u >> 16) & 1u)) >> 16);   // RNE
}
__device__ inline float bf2f(unsigned short h) {
    unsigned int u = ((unsigned int)h) << 16;
    return __builtin_bit_cast(float, u);
}

__device__ inline void gload_lds16(const void* g, void* l) {
    __builtin_amdgcn_global_load_lds(
        (const __attribute__((address_space(1))) unsigned int*)g,
        (__attribute__((address_space(3))) unsigned int*)l, 16, 0, 0);
}

// ---------------------------------------------------------------------------
// Prep: w (fp32) -> wt: MFMA-fragment-ordered bf16 hi/lo tiles + wsqh.
// Layout (shorts): wt[ch*14336 + nf*1024 + hl*512 + l*8 + pos] where for
// element w[k][c]: ch=c/32, nf=k/16, l=(k&15)|(((c&31)>>3)<<4), pos=c&7.
// Lane l of a wave then reads its B-fragment as 16B at (nf,hl) tile + l*16.
// wsqh reduction order identical to round-1's proven-matching kernel.
// ---------------------------------------------------------------------------
__global__ void wprep_kernel(const float* __restrict__ w,
                             short* __restrict__ wt,
                             float* __restrict__ wsqh) {
    const int k = blockIdx.x, lane = threadIdx.x;    // 224 blocks x 64
    float s = 0.f;
    for (int c = lane; c < CH; c += 64) {
        const float v = w[k * CH + c];
        const unsigned short h = f2bf(v);
        const unsigned short lo = f2bf(v - bf2f(h));
        const int base = (c >> 5) * 14336 + (k >> 4) * 1024
                       + (((k & 15) | (((c & 31) >> 3) << 4)) * 8) + (c & 7);
        wt[base]       = (short)h;     // hl = 0
        wt[base + 512] = (short)lo;    // hl = 1
        s = fmaf(v, v, s);
    }
    for (int off = 32; off > 0; off >>= 1) s += __shfl_down(s, off);
    if (lane == 0) wsqh[k] = 0.5f * s;
}

// ---------------------------------------------------------------------------
// Main: block = 128 rows x 224 codes. X fragments loaded straight from
// global into registers (no X LDS). W staged via global_load_lds from the
// pre-fragmented wt image (linear copy, conflict-free ds_read_b128).
// score = x.w - 0.5||w||^2 via 3x bf16 MFMA; fused argmax + one-hot;
// gap < EPS rows re-resolved exactly in fp32 (round-1 proven math).
// ---------------------------------------------------------------------------
__global__ __launch_bounds__(256, 3) void som_mfma(
    const float* __restrict__ inp, const float* __restrict__ w,
    const short* __restrict__ wt, const float* __restrict__ wsqh,
    float* __restrict__ out)
{
    __shared__ __align__(16) short Wl[NF * 2 * 64 * 8];   // 28672 B
    __shared__ int bmu_sh[MB];
    __shared__ unsigned char flg_sh[MB];

    const int tid  = threadIdx.x;
    const int lane = tid & 63;
    const int wv   = tid >> 6;
    const int m0   = blockIdx.x * MB;
    const int mw   = m0 + wv * 32;           // 32-aligned -> single b per wave
    const int bb   = mw / CH;
    const int t0   = mw % CH;
    const int col  = lane & 15;
    const int g    = lane >> 4;

    const float* xbase = inp + (size_t)bb * CH * CH + t0 + col;

    f32x4 acc[2][NF];
    #pragma unroll
    for (int mf = 0; mf < 2; ++mf)
        #pragma unroll
        for (int nf = 0; nf < NF; ++nf)
            acc[mf][nf] = (f32x4){0.f, 0.f, 0.f, 0.f};

    for (int ch = 0; ch < 7; ++ch) {
        const int cb = ch * 32;

        // ---- X fragment loads (global -> regs, issued before the barrier) ----
        float xv[2][8];
        #pragma unroll
        for (int mf = 0; mf < 2; ++mf)
            #pragma unroll
            for (int j = 0; j < 8; ++j)
                xv[mf][j] = xbase[(size_t)(cb + g * 8 + j) * CH + mf * 16];

        __syncthreads();   // all waves done reading Wl of previous chunk

        // ---- W stage: linear async copy, 7x 1KB per wave ----
        {
            const char* gsrc = (const char*)wt + ch * 28672 + wv * 7168 + lane * 16;
            char* ldst = (char*)&Wl[0] + wv * 7168;
            #pragma unroll
            for (int p = 0; p < 7; ++p)
                gload_lds16(gsrc + p * 1024, ldst + p * 1024);
        }

        // ---- convert X to hi/lo bf16 fragments ----
        bf16x8 afh[2], afl[2];
        #pragma unroll
        for (int mf = 0; mf < 2; ++mf)
            #pragma unroll
            for (int j = 0; j < 8; ++j) {
                const unsigned short h = f2bf(xv[mf][j]);
                afh[mf][j] = (short)h;
                afl[mf][j] = (short)f2bf(xv[mf][j] - bf2f(h));
            }

        __syncthreads();   // vmcnt(0) drain + barrier: Wl ready

        // ---- MFMA: conflict-free ds_read_b128 at lane*16 ----
        #pragma unroll
        for (int nf = 0; nf < NF; ++nf) {
            const bf16x8 bh = *(const bf16x8*)(Wl + nf * 1024 + lane * 8);
            const bf16x8 bl = *(const bf16x8*)(Wl + nf * 1024 + 512 + lane * 8);
            #pragma unroll
            for (int mf = 0; mf < 2; ++mf) {
                acc[mf][nf] = __builtin_amdgcn_mfma_f32_16x16x32_bf16(afh[mf], bh, acc[mf][nf], 0, 0, 0);
                acc[mf][nf] = __builtin_amdgcn_mfma_f32_16x16x32_bf16(afh[mf], bl, acc[mf][nf], 0, 0, 0);
                acc[mf][nf] = __builtin_amdgcn_mfma_f32_16x16x32_bf16(afl[mf], bh, acc[mf][nf], 0, 0, 0);
            }
        }
    }

    // ---- fused argmax with top-2 gap flag (C layout: col=lane&15, row=g*4+r) ----
    float wq[NF];
    #pragma unroll
    for (int nf = 0; nf < NF; ++nf) wq[nf] = wsqh[nf * 16 + col];

    #pragma unroll
    for (int mf = 0; mf < 2; ++mf) {
        #pragma unroll
        for (int r = 0; r < 4; ++r) {
            float v1 = -1e30f, v2 = -1e30f; int k1 = 0;
            #pragma unroll
            for (int nf = 0; nf < NF; ++nf) {
                const float s = acc[mf][nf][r] - wq[nf];
                const int k = nf * 16 + col;
                if (s > v1 || (s == v1 && k < k1)) { v2 = v1; v1 = s; k1 = k; }
                else if (s > v2) v2 = s;
            }
            #pragma unroll
            for (int mm = 1; mm < 16; mm <<= 1) {
                const float ov1 = __shfl_xor(v1, mm);
                const int   ok1 = __shfl_xor(k1, mm);
                const float ov2 = __shfl_xor(v2, mm);
                if (ov1 > v1 || (ov1 == v1 && ok1 < k1)) { v2 = fmaxf(v1, ov2); v1 = ov1; k1 = ok1; }
                else                                     { v2 = fmaxf(v2, ov1); }
            }
            if (col == 0) {
                const int trow = mf * 16 + g * 4 + r;
                bmu_sh[wv * 32 + trow] = k1;
                flg_sh[wv * 32 + trow] = (v1 - v2 < EPS) ? 1 : 0;
            }
        }
    }

    // ---- exact re-resolve of flagged rows (rare; replicates round-1 math) ----
    for (int tl = 0; tl < 32; ++tl) {
        if (!flg_sh[wv * 32 + tl]) continue;
        const int tg = t0 + tl;
        const float* xp = inp + (size_t)bb * CH * CH + tg;
        float s0 = 0.f, s1 = 0.f, s2 = 0.f, s3 = 0.f;
        const int k0 = lane, k1a = lane + 64, k2 = lane + 128, k3 = lane + 192;
        for (int c = 0; c < CH; c += 4) {
            float xc[4];
            #pragma unroll
            for (int i = 0; i < 4; ++i) xc[i] = xp[(size_t)(c + i) * CH];
            const float4 w0 = *(const float4*)(w + (size_t)k0  * CH + c);
            const float4 w1 = *(const float4*)(w + (size_t)k1a * CH + c);
            const float4 w2 = *(const float4*)(w + (size_t)k2  * CH + c);
            s0 = fmaf(xc[0], w0.x, s0); s0 = fmaf(xc[1], w0.y, s0); s0 = fmaf(xc[2], w0.z, s0); s0 = fmaf(xc[3], w0.w, s0);
            s1 = fmaf(xc[0], w1.x, s1); s1 = fmaf(xc[1], w1.y, s1); s1 = fmaf(xc[2], w1.z, s1); s1 = fmaf(xc[3], w1.w, s1);
            s2 = fmaf(xc[0], w2.x, s2); s2 = fmaf(xc[1], w2.y, s2); s2 = fmaf(xc[2], w2.z, s2); s2 = fmaf(xc[3], w2.w, s2);
            if (k3 < CH) {
                const float4 w3 = *(const float4*)(w + (size_t)k3 * CH + c);
                s3 = fmaf(xc[0], w3.x, s3); s3 = fmaf(xc[1], w3.y, s3); s3 = fmaf(xc[2], w3.z, s3); s3 = fmaf(xc[3], w3.w, s3);
            }
        }
        float bs = -1e30f; int bk = 1 << 30;
        {
            const float c0v = s0 - wsqh[k0];
            if (c0v > bs || (c0v == bs && k0 < bk)) { bs = c0v; bk = k0; }
            const float c1v = s1 - wsqh[k1a];
            if (c1v > bs || (c1v == bs && k1a < bk)) { bs = c1v; bk = k1a; }
            const float c2v = s2 - wsqh[k2];
            if (c2v > bs || (c2v == bs && k2 < bk)) { bs = c2v; bk = k2; }
            if (k3 < CH) {
                const float c3v = s3 - wsqh[k3];
                if (c3v > bs || (c3v == bs && k3 < bk)) { bs = c3v; bk = k3; }
            }
        }
        for (int mm = 1; mm < 64; mm <<= 1) {
            const float ob = __shfl_xor(bs, mm);
            const int   ok = __shfl_xor(bk, mm);
            if (ob > bs || (ob == bs && ok < bk)) { bs = ob; bk = ok; }
        }
        if (lane == 0) bmu_sh[wv * 32 + tl] = bk;
    }

    __syncthreads();

    // ---- one-hot write: out[b, k, t] ----
    #pragma unroll
    for (int j = 0; j < 28; ++j) {
        const int f  = tid + 256 * j;       // 0..7167
        const int k  = f >> 5;              // 0..223
        const int rg = f & 31;              // 4-row group (never crosses b)
        const int m  = m0 + rg * 4;
        const int b2 = m / CH, t = m % CH;
        float4 v;
        v.x = (bmu_sh[rg * 4 + 0] == k) ? 1.f : 0.f;
        v.y = (bmu_sh[rg * 4 + 1] == k) ? 1.f : 0.f;
        v.z = (bmu_sh[rg * 4 + 2] == k) ? 1.f : 0.f;
        v.w = (bmu_sh[rg * 4 + 3] == k) ? 1.f : 0.f;
        *(float4*)(out + (size_t)b2 * CH * CH + (size_t)k * CH + t) = v;
    }
}

extern "C" void kernel_launch(void* const* d_in, const int* in_sizes, int n_in,
                              void* d_out, int out_size, void* d_ws, size_t ws_size,
                              hipStream_t stream) {
    const float* inp = (const float*)d_in[0];   // (512, 224, 224) fp32
    const float* w   = (const float*)d_in[1];   // (224, 224) fp32
    float* out = (float*)d_out;

    short* wt   = (short*)d_ws;                 // 7*14*2*64*8 = 100352 shorts
    float* wsqh = (float*)(wt + 7 * 14 * 2 * 64 * 8);   // 224 fp32

    const int batch = in_sizes[0] / (CH * CH);  // 512
    const int mtot  = batch * CH;               // 114688

    wprep_kernel<<<CH, 64, 0, stream>>>(w, wt, wsqh);
    som_mfma<<<mtot / MB, 256, 0, stream>>>(inp, w, wt, wsqh, out);
}